// Round 2
// baseline (1565.326 us; speedup 1.0000x reference)
//
#include <hip/hip_runtime.h>
#include <hip/hip_bf16.h>

#define T_TOK 8192
#define DDIM 1024
#define HDIM 4096

typedef __bf16 bf16;
typedef bf16 bf16x8 __attribute__((ext_vector_type(8)));
typedef float f32x4 __attribute__((ext_vector_type(4)));

#define ASM_VMCNT(n) asm volatile("s_waitcnt vmcnt(" #n ")" ::: "memory")

__device__ __forceinline__ void gl_lds16(const void* g, void* l) {
  __builtin_amdgcn_global_load_lds(
      (const __attribute__((address_space(1))) unsigned int*)g,
      (__attribute__((address_space(3))) unsigned int*)l, 16, 0, 0);
}

// ---------------- x fp32 -> bf16 ----------------
__global__ __launch_bounds__(256) void convert_x(const float* __restrict__ x,
                                                 bf16* __restrict__ xb) {
  const size_t i = ((size_t)blockIdx.x * 256 + threadIdx.x) * 8;
  const float4 v0 = *(const float4*)(x + i);
  const float4 v1 = *(const float4*)(x + i + 4);
  bf16x8 o;
  o[0] = (bf16)v0.x; o[1] = (bf16)v0.y; o[2] = (bf16)v0.z; o[3] = (bf16)v0.w;
  o[4] = (bf16)v1.x; o[5] = (bf16)v1.y; o[6] = (bf16)v1.z; o[7] = (bf16)v1.w;
  *(bf16x8*)(xb + i) = o;
}

// ---------------- weight transpose + convert: src [R,C] f32 -> dst [C,R] bf16
__global__ __launch_bounds__(256) void transpose_convert(
    const float* __restrict__ src, bf16* __restrict__ dst, int R, int C) {
  __shared__ float tile[32][33];
  const size_t mat = (size_t)blockIdx.z * R * C;
  const int c0 = blockIdx.x * 32, r0 = blockIdx.y * 32;
  const int tx = threadIdx.x & 31, ty = threadIdx.x >> 5;  // 32 x 8
#pragma unroll
  for (int i = 0; i < 4; ++i)
    tile[ty + 8 * i][tx] =
        src[mat + (size_t)(r0 + ty + 8 * i) * C + c0 + tx];
  __syncthreads();
#pragma unroll
  for (int i = 0; i < 4; ++i)
    dst[mat + (size_t)(c0 + ty + 8 * i) * R + r0 + tx] =
        (bf16)tile[tx][ty + 8 * i];
}

// ---------------- router: softmax/top2/gates + aux sums ----------------
__global__ __launch_bounds__(256) void router_kernel(
    const float* __restrict__ x, const float* __restrict__ srw,
    const float* __restrict__ srb, const float* __restrict__ hrw,
    const float* __restrict__ hrb, float* __restrict__ gate,
    float* __restrict__ auxg) {
  __shared__ float saux[8];
  if (threadIdx.x < 8) saux[threadIdx.x] = 0.0f;
  __syncthreads();

  const int lane = threadIdx.x & 63;
  const int w = threadIdx.x >> 6;
  const int t = blockIdx.x * 4 + w;

  const float* xr = x + (size_t)t * DDIM;
  float p0 = 0, p1 = 0, p2 = 0, p3 = 0, p4 = 0, p5 = 0;
#pragma unroll
  for (int c = 0; c < 4; ++c) {
    const int d = c * 256 + lane * 4;
    const float4 xv = *(const float4*)(xr + d);
    const float xa[4] = {xv.x, xv.y, xv.z, xv.w};
#pragma unroll
    for (int j = 0; j < 4; ++j) {
      const float xd = xa[j];
      const float4 r4 = *(const float4*)(srw + (size_t)(d + j) * 4);
      p0 += xd * r4.x; p1 += xd * r4.y; p2 += xd * r4.z; p3 += xd * r4.w;
      const float2 r2 = *(const float2*)(hrw + (size_t)(d + j) * 2);
      p4 += xd * r2.x; p5 += xd * r2.y;
    }
  }
#pragma unroll
  for (int off = 32; off >= 1; off >>= 1) {
    p0 += __shfl_xor(p0, off);
    p1 += __shfl_xor(p1, off);
    p2 += __shfl_xor(p2, off);
    p3 += __shfl_xor(p3, off);
    p4 += __shfl_xor(p4, off);
    p5 += __shfl_xor(p5, off);
  }
  if (lane == 0) {
    const float l0 = p0 + srb[0], l1 = p1 + srb[1];
    const float l2 = p2 + srb[2], l3 = p3 + srb[3];
    const float m = fmaxf(fmaxf(l0, l1), fmaxf(l2, l3));
    const float e0 = expf(l0 - m), e1 = expf(l1 - m);
    const float e2 = expf(l2 - m), e3 = expf(l3 - m);
    const float s = e0 + e1 + e2 + e3;
    float pr[4] = {e0 / s, e1 / s, e2 / s, e3 / s};
    int i1 = 0; float v1 = pr[0];
#pragma unroll
    for (int e = 1; e < 4; ++e) if (pr[e] > v1) { v1 = pr[e]; i1 = e; }
    int i2 = -1; float v2 = -1.0f;
#pragma unroll
    for (int e = 0; e < 4; ++e)
      if (e != i1 && pr[e] > v2) { v2 = pr[e]; i2 = e; }
    float g[4] = {0, 0, 0, 0};
    g[i1] = v1; g[i2] = v2;
    float* gr = gate + (size_t)t * 8;
    gr[0] = g[0]; gr[1] = g[1]; gr[2] = g[2]; gr[3] = g[3];
    const float h0 = p4 + hrb[0], h1 = p5 + hrb[1];
    const float mh = fmaxf(h0, h1);
    const float q0 = expf(h0 - mh), q1 = expf(h1 - mh);
    const float qs = q0 + q1;
    gr[4] = q0 / qs; gr[5] = q1 / qs; gr[6] = 0; gr[7] = 0;
    atomicAdd(&saux[i1], 1.0f);
    atomicAdd(&saux[i2], 1.0f);
    atomicAdd(&saux[4 + 0], pr[0]);
    atomicAdd(&saux[4 + 1], pr[1]);
    atomicAdd(&saux[4 + 2], pr[2]);
    atomicAdd(&saux[4 + 3], pr[3]);
  }
  __syncthreads();
  if (threadIdx.x < 8) atomicAdd(&auxg[threadIdx.x], saux[threadIdx.x]);
}

__global__ void init_aux(float* auxg) {
  if (threadIdx.x < 8) auxg[threadIdx.x] = 0.0f;
}

__global__ void aux_finalize(const float* __restrict__ auxg,
                             float* __restrict__ outp) {
  float a = 0.0f;
#pragma unroll
  for (int e = 0; e < 4; ++e)
    a += (auxg[e] / (float)(T_TOK * 2)) * (auxg[4 + e] / (float)T_TOK);
  outp[0] = 4.0f * a;
}

// ---------------- pipelined GEMM  C = A[M,K] * B[N,K]^T  (bf16 in, f32 acc)
// BM=256 rows, BK=32, 8 waves (2M x 4N), 4-deep LDS ring, counted vmcnt,
// XOR-swizzled LDS (byte ^= (row&3)<<4 within 64B rows).
// MODE 0: Hout = gelu(C + bias)            (bf16)
// MODE 1: Fout += gate[:,gidx] * (C + bias)
// MODE 2: Fout  = gate[:,gidx] * (C + bias)
template <int BN_, int MODE>
__global__ __launch_bounds__(512, 2) void gemm8p(
    const bf16* __restrict__ A, const bf16* __restrict__ B, int M, int N,
    int K, const float* __restrict__ bias, bf16* __restrict__ Hout,
    float* __restrict__ Fout, const float* __restrict__ gate, int gidx) {
  constexpr int WN_TILE = BN_ / 4;     // per-wave N extent
  constexpr int NREP = BN_ / 64;       // 4 (BN256) or 2 (BN128)
  constexpr int CHUNKS_B = BN_ / 128;  // 2 or 1 (8KB staging chunks for B)
  constexpr int SLOTB = CHUNKS_B * 8192;

  __shared__ bf16 Alds[4 * 256 * 32];   // 64 KB, 4-slot ring
  __shared__ bf16 Blds[4 * BN_ * 32];   // 64/32 KB

  const int tid = threadIdx.x;
  const int lane = tid & 63, wid = tid >> 6;
  const int wm = wid >> 2, wn = wid & 3;
  const int lr = lane & 15, lg = lane >> 4;

  const int MB = M >> 8;
  const int cpx = gridDim.x >> 3;  // grid always divisible by 8 here
  const int id2 = (blockIdx.x & 7) * cpx + (blockIdx.x >> 3);
  const int bm = id2 % MB, bn = id2 / MB;

  const int NT = K >> 5;

  // ---- staging source addresses (pre-swizzled global, linear LDS dest) ----
  const int L = tid * 16;                       // byte within 8KB chunk
  const int rl = L >> 6;                        // row within chunk (64B rows)
  const int cbs = (L & 63) ^ ((rl & 3) << 4);   // logical col byte
  const bf16* sA0 = A + (size_t)(bm * 256 + rl) * K + (cbs >> 1);
  const bf16* sA1 = A + (size_t)(bm * 256 + 128 + rl) * K + (cbs >> 1);
  const bf16* sB0 = B + (size_t)(bn * BN_ + rl) * K + (cbs >> 1);
  const bf16* sB1 = B + (size_t)(bn * BN_ + (CHUNKS_B == 2 ? 128 : 0) + rl) * K + (cbs >> 1);

  char* ldsA = (char*)Alds;
  char* ldsB = (char*)Blds;
  const int wb = wid * 1024;  // wave-uniform dest offset

  // ---- ds_read bases (swizzled) ----
  const int cbr = (lg * 16) ^ ((lr & 3) << 4);
  const char* ArdB = (const char*)Alds + (wm * 128 + lr) * 64 + cbr;
  const char* BrdB = (const char*)Blds + (wn * WN_TILE + lr) * 64 + cbr;

  f32x4 acc[8][NREP] = {};

  // ---- prologue: stage tiles 0,1,2 ----
#pragma unroll
  for (int t = 0; t < 3; ++t) {
    const size_t ko = (size_t)t << 5;
    gl_lds16(sA0 + ko, ldsA + t * 16384 + wb);
    gl_lds16(sA1 + ko, ldsA + t * 16384 + 8192 + wb);
    gl_lds16(sB0 + ko, ldsB + t * SLOTB + wb);
    if constexpr (CHUNKS_B == 2)
      gl_lds16(sB1 + ko, ldsB + t * SLOTB + 8192 + wb);
  }
  if constexpr (CHUNKS_B == 2) ASM_VMCNT(8); else ASM_VMCNT(6);
  __builtin_amdgcn_s_barrier();

  bf16x8 bfrag[NREP];
  for (int kt = 0; kt < NT; ++kt) {
    const int sA = (kt & 3) * 16384;
    const int sB = (kt & 3) * SLOTB;
    const bool st = (kt + 3) < NT;
    const int dsl = (kt + 3) & 3;
    const size_t ko = (size_t)(kt + 3) << 5;

    // ---- phase A: m-frags 0..3 ----
    bf16x8 af[4];
#pragma unroll
    for (int mf = 0; mf < 4; ++mf)
      af[mf] = *(const bf16x8*)(ArdB + sA + mf * 1024);
#pragma unroll
    for (int nf = 0; nf < NREP; ++nf)
      bfrag[nf] = *(const bf16x8*)(BrdB + sB + nf * 1024);
    if (st) {
      gl_lds16(sA0 + ko, ldsA + dsl * 16384 + wb);
      gl_lds16(sA1 + ko, ldsA + dsl * 16384 + 8192 + wb);
    }
    __builtin_amdgcn_s_barrier();
    asm volatile("s_waitcnt lgkmcnt(0)" ::: "memory");
    __builtin_amdgcn_sched_barrier(0);
    __builtin_amdgcn_s_setprio(1);
#pragma unroll
    for (int mf = 0; mf < 4; ++mf)
#pragma unroll
      for (int nf = 0; nf < NREP; ++nf)
        acc[mf][nf] = __builtin_amdgcn_mfma_f32_16x16x32_bf16(
            af[mf], bfrag[nf], acc[mf][nf], 0, 0, 0);
    __builtin_amdgcn_s_setprio(0);
    __builtin_amdgcn_s_barrier();

    // ---- phase B: m-frags 4..7 ----
#pragma unroll
    for (int mf = 0; mf < 4; ++mf)
      af[mf] = *(const bf16x8*)(ArdB + sA + (4 + mf) * 1024);
    if (st) {
      gl_lds16(sB0 + ko, ldsB + dsl * SLOTB + wb);
      if constexpr (CHUNKS_B == 2)
        gl_lds16(sB1 + ko, ldsB + dsl * SLOTB + 8192 + wb);
    }
    __builtin_amdgcn_s_barrier();
    asm volatile("s_waitcnt lgkmcnt(0)" ::: "memory");
    __builtin_amdgcn_sched_barrier(0);
    __builtin_amdgcn_s_setprio(1);
#pragma unroll
    for (int mf = 0; mf < 4; ++mf)
#pragma unroll
      for (int nf = 0; nf < NREP; ++nf)
        acc[4 + mf][nf] = __builtin_amdgcn_mfma_f32_16x16x32_bf16(
            af[mf], bfrag[nf], acc[4 + mf][nf], 0, 0, 0);
    __builtin_amdgcn_s_setprio(0);
    // tile-end counted wait: next tile resident; prefetched loads stay in flight
    if (st) {
      if constexpr (CHUNKS_B == 2) ASM_VMCNT(8); else ASM_VMCNT(6);
    } else if (kt + 2 < NT) {
      if constexpr (CHUNKS_B == 2) ASM_VMCNT(4); else ASM_VMCNT(3);
    } else if (kt + 1 < NT) {
      ASM_VMCNT(0);
    }
    __builtin_amdgcn_s_barrier();
  }

  // ---- epilogue ----
  const int colb = bn * BN_ + wn * WN_TILE;
  const int rowb = bm * 256 + wm * 128 + lg * 4;
#pragma unroll
  for (int mf = 0; mf < 8; ++mf) {
#pragma unroll
    for (int nf = 0; nf < NREP; ++nf) {
      const int col = colb + nf * 16 + lr;
      const float bv = bias[col];
#pragma unroll
      for (int r = 0; r < 4; ++r) {
        const int row = rowb + mf * 16 + r;
        const float v = acc[mf][nf][r] + bv;
        if (MODE == 0) {
          const float gl = 0.5f * v * (1.0f + erff(v * 0.7071067811865475f));
          Hout[(size_t)row * N + col] = (bf16)gl;
        } else {
          const float gv = gate[(size_t)row * 8 + gidx];
          const size_t oi = (size_t)row * N + col;
          if (MODE == 1)
            Fout[oi] += gv * v;
          else
            Fout[oi] = gv * v;
        }
      }
    }
  }
}

extern "C" void kernel_launch(void* const* d_in, const int* in_sizes, int n_in,
                              void* d_out, int out_size, void* d_ws,
                              size_t ws_size, hipStream_t stream) {
  const float* x = (const float*)d_in[0];
  const float* spec_w1 = (const float*)d_in[1];
  const float* spec_b1 = (const float*)d_in[2];
  const float* spec_w2 = (const float*)d_in[3];
  const float* spec_b2 = (const float*)d_in[4];
  const float* spec_rw = (const float*)d_in[5];
  const float* spec_rb = (const float*)d_in[6];
  const float* shr_w1 = (const float*)d_in[7];
  const float* shr_b1 = (const float*)d_in[8];
  const float* shr_w2 = (const float*)d_in[9];
  const float* shr_b2 = (const float*)d_in[10];
  const float* shr_rw = (const float*)d_in[11];
  const float* shr_rb = (const float*)d_in[12];
  float* out = (float*)d_out;

  char* ws = (char*)d_ws;
  const size_t SZ_X = (size_t)T_TOK * DDIM * 2;
  const size_t SZ_W = (size_t)6 * DDIM * HDIM * 2;
  bf16* xb = (bf16*)ws;
  bf16* w1t = (bf16*)(ws + SZ_X);
  bf16* w2t = (bf16*)(ws + SZ_X + SZ_W);
  bf16* hbuf = (bf16*)(ws + SZ_X + 2 * SZ_W);
  float* gate = (float*)(ws + SZ_X + 2 * SZ_W + (size_t)T_TOK * HDIM * 2);
  float* auxg = gate + (size_t)T_TOK * 8;

  init_aux<<<1, 64, 0, stream>>>(auxg);
  convert_x<<<(T_TOK * DDIM) / 2048, 256, 0, stream>>>(x, xb);
  transpose_convert<<<dim3(HDIM / 32, DDIM / 32, 4), 256, 0, stream>>>(
      spec_w1, w1t, DDIM, HDIM);
  transpose_convert<<<dim3(HDIM / 32, DDIM / 32, 2), 256, 0, stream>>>(
      shr_w1, w1t + (size_t)4 * DDIM * HDIM, DDIM, HDIM);
  transpose_convert<<<dim3(DDIM / 32, HDIM / 32, 4), 256, 0, stream>>>(
      spec_w2, w2t, HDIM, DDIM);
  transpose_convert<<<dim3(DDIM / 32, HDIM / 32, 2), 256, 0, stream>>>(
      shr_w2, w2t + (size_t)4 * DDIM * HDIM, HDIM, DDIM);
  router_kernel<<<T_TOK / 4, 256, 0, stream>>>(x, spec_rw, spec_rb, shr_rw,
                                               shr_rb, gate, auxg);

  for (int e = 0; e < 6; ++e) {
    const bf16* w1e = w1t + (size_t)e * DDIM * HDIM;
    const bf16* w2e = w2t + (size_t)e * DDIM * HDIM;
    const float* b1e =
        (e < 4) ? spec_b1 + (size_t)e * HDIM : shr_b1 + (size_t)(e - 4) * HDIM;
    const float* b2e =
        (e < 4) ? spec_b2 + (size_t)e * DDIM : shr_b2 + (size_t)(e - 4) * DDIM;

    // gemm1: [8192,1024] x [4096,1024]^T -> h [8192,4096], grid 32x16=512
    gemm8p<256, 0><<<512, 512, 0, stream>>>(xb, w1e, T_TOK, HDIM, DDIM, b1e,
                                            hbuf, nullptr, nullptr, 0);
    // gemm2: [8192,4096] x [1024,4096]^T -> out, grid 32x8=256 (1 block/CU)
    if (e == 0)
      gemm8p<128, 2><<<256, 512, 0, stream>>>(hbuf, w2e, T_TOK, DDIM, HDIM,
                                              b2e, nullptr, out, gate, e);
    else
      gemm8p<128, 1><<<256, 512, 0, stream>>>(hbuf, w2e, T_TOK, DDIM, HDIM,
                                              b2e, nullptr, out, gate, e);
  }
  aux_finalize<<<1, 1, 0, stream>>>(auxg, out + (size_t)T_TOK * DDIM);
}

// Round 3
// 1321.229 us; speedup vs baseline: 1.1848x; 1.1848x over previous
//
#include <hip/hip_runtime.h>
#include <hip/hip_bf16.h>

#define T_TOK 8192
#define DDIM 1024
#define HDIM 4096

typedef __bf16 bf16;
typedef bf16 bf16x8 __attribute__((ext_vector_type(8)));
typedef float f32x4 __attribute__((ext_vector_type(4)));

#define ASM_VMCNT(n) asm volatile("s_waitcnt vmcnt(" #n ")" ::: "memory")

__device__ __forceinline__ void gl_lds16(const void* g, void* l) {
  __builtin_amdgcn_global_load_lds(
      (const __attribute__((address_space(1))) unsigned int*)g,
      (__attribute__((address_space(3))) unsigned int*)l, 16, 0, 0);
}

// ---------------- x fp32 -> bf16 ----------------
__global__ __launch_bounds__(256) void convert_x(const float* __restrict__ x,
                                                 bf16* __restrict__ xb) {
  const size_t i = ((size_t)blockIdx.x * 256 + threadIdx.x) * 8;
  const float4 v0 = *(const float4*)(x + i);
  const float4 v1 = *(const float4*)(x + i + 4);
  bf16x8 o;
  o[0] = (bf16)v0.x; o[1] = (bf16)v0.y; o[2] = (bf16)v0.z; o[3] = (bf16)v0.w;
  o[4] = (bf16)v1.x; o[5] = (bf16)v1.y; o[6] = (bf16)v1.z; o[7] = (bf16)v1.w;
  *(bf16x8*)(xb + i) = o;
}

// ---------------- weight transpose + convert: src [R,C] f32 -> dst [C,R] bf16
__global__ __launch_bounds__(256) void transpose_convert(
    const float* __restrict__ src, bf16* __restrict__ dst, int R, int C) {
  __shared__ float tile[32][33];
  const size_t mat = (size_t)blockIdx.z * R * C;
  const int c0 = blockIdx.x * 32, r0 = blockIdx.y * 32;
  const int tx = threadIdx.x & 31, ty = threadIdx.x >> 5;  // 32 x 8
#pragma unroll
  for (int i = 0; i < 4; ++i)
    tile[ty + 8 * i][tx] =
        src[mat + (size_t)(r0 + ty + 8 * i) * C + c0 + tx];
  __syncthreads();
#pragma unroll
  for (int i = 0; i < 4; ++i)
    dst[mat + (size_t)(c0 + ty + 8 * i) * R + r0 + tx] =
        (bf16)tile[tx][ty + 8 * i];
}

// ---------------- router: softmax/top2/gates + aux sums ----------------
__global__ __launch_bounds__(256) void router_kernel(
    const float* __restrict__ x, const float* __restrict__ srw,
    const float* __restrict__ srb, const float* __restrict__ hrw,
    const float* __restrict__ hrb, float* __restrict__ gate,
    float* __restrict__ auxg) {
  __shared__ float saux[8];
  if (threadIdx.x < 8) saux[threadIdx.x] = 0.0f;
  __syncthreads();

  const int lane = threadIdx.x & 63;
  const int w = threadIdx.x >> 6;
  const int t = blockIdx.x * 4 + w;

  const float* xr = x + (size_t)t * DDIM;
  float p0 = 0, p1 = 0, p2 = 0, p3 = 0, p4 = 0, p5 = 0;
#pragma unroll
  for (int c = 0; c < 4; ++c) {
    const int d = c * 256 + lane * 4;
    const float4 xv = *(const float4*)(xr + d);
    const float xa[4] = {xv.x, xv.y, xv.z, xv.w};
#pragma unroll
    for (int j = 0; j < 4; ++j) {
      const float xd = xa[j];
      const float4 r4 = *(const float4*)(srw + (size_t)(d + j) * 4);
      p0 += xd * r4.x; p1 += xd * r4.y; p2 += xd * r4.z; p3 += xd * r4.w;
      const float2 r2 = *(const float2*)(hrw + (size_t)(d + j) * 2);
      p4 += xd * r2.x; p5 += xd * r2.y;
    }
  }
#pragma unroll
  for (int off = 32; off >= 1; off >>= 1) {
    p0 += __shfl_xor(p0, off);
    p1 += __shfl_xor(p1, off);
    p2 += __shfl_xor(p2, off);
    p3 += __shfl_xor(p3, off);
    p4 += __shfl_xor(p4, off);
    p5 += __shfl_xor(p5, off);
  }
  if (lane == 0) {
    const float l0 = p0 + srb[0], l1 = p1 + srb[1];
    const float l2 = p2 + srb[2], l3 = p3 + srb[3];
    const float m = fmaxf(fmaxf(l0, l1), fmaxf(l2, l3));
    const float e0 = expf(l0 - m), e1 = expf(l1 - m);
    const float e2 = expf(l2 - m), e3 = expf(l3 - m);
    const float s = e0 + e1 + e2 + e3;
    float pr[4] = {e0 / s, e1 / s, e2 / s, e3 / s};
    int i1 = 0; float v1 = pr[0];
#pragma unroll
    for (int e = 1; e < 4; ++e) if (pr[e] > v1) { v1 = pr[e]; i1 = e; }
    int i2 = -1; float v2 = -1.0f;
#pragma unroll
    for (int e = 0; e < 4; ++e)
      if (e != i1 && pr[e] > v2) { v2 = pr[e]; i2 = e; }
    float g[4] = {0, 0, 0, 0};
    g[i1] = v1; g[i2] = v2;
    float* gr = gate + (size_t)t * 8;
    gr[0] = g[0]; gr[1] = g[1]; gr[2] = g[2]; gr[3] = g[3];
    const float h0 = p4 + hrb[0], h1 = p5 + hrb[1];
    const float mh = fmaxf(h0, h1);
    const float q0 = expf(h0 - mh), q1 = expf(h1 - mh);
    const float qs = q0 + q1;
    gr[4] = q0 / qs; gr[5] = q1 / qs; gr[6] = 0; gr[7] = 0;
    atomicAdd(&saux[i1], 1.0f);
    atomicAdd(&saux[i2], 1.0f);
    atomicAdd(&saux[4 + 0], pr[0]);
    atomicAdd(&saux[4 + 1], pr[1]);
    atomicAdd(&saux[4 + 2], pr[2]);
    atomicAdd(&saux[4 + 3], pr[3]);
  }
  __syncthreads();
  if (threadIdx.x < 8) atomicAdd(&auxg[threadIdx.x], saux[threadIdx.x]);
}

__global__ void init_aux(float* auxg) {
  if (threadIdx.x < 8) auxg[threadIdx.x] = 0.0f;
}

__global__ void aux_finalize(const float* __restrict__ auxg,
                             float* __restrict__ outp) {
  float a = 0.0f;
#pragma unroll
  for (int e = 0; e < 4; ++e)
    a += (auxg[e] / (float)(T_TOK * 2)) * (auxg[4 + e] / (float)T_TOK);
  outp[0] = 4.0f * a;
}

// ---------------- pipelined GEMM  C = A[M,K] * B[N,K]^T  (bf16 in, f32 acc)
// BM=256 rows, BK=32, 8 waves (2M x 4N), 4-deep LDS ring, counted vmcnt,
// quarter-wave-balanced XOR swizzle (byte ^= ((row>>1)&3)<<4 in 64B rows),
// 2D chunk XCD mapping (each XCD owns a CH_M x CH_N block chunk).
// MODE 0: Hout = gelu(C + bias)            (bf16)
// MODE 1: Fout += gate[:,gidx] * (C + bias)
// MODE 2: Fout  = gate[:,gidx] * (C + bias)
template <int BN_, int MODE>
__global__ __launch_bounds__(512, 2) void gemm8p(
    const bf16* __restrict__ A, const bf16* __restrict__ B, int M, int N,
    int K, const float* __restrict__ bias, bf16* __restrict__ Hout,
    float* __restrict__ Fout, const float* __restrict__ gate, int gidx,
    int NBn, int CH_M, int CH_N) {
  constexpr int WN_TILE = BN_ / 4;     // per-wave N extent
  constexpr int NREP = BN_ / 64;       // 4 (BN256) or 2 (BN128)
  constexpr int CHUNKS_B = BN_ / 128;  // 2 or 1 (8KB staging chunks for B)
  constexpr int SLOTB = CHUNKS_B * 8192;

  __shared__ bf16 Alds[4 * 256 * 32];   // 64 KB, 4-slot ring
  __shared__ bf16 Blds[4 * BN_ * 32];   // 64/32 KB

  const int tid = threadIdx.x;
  const int lane = tid & 63, wid = tid >> 6;
  const int wm = wid >> 2, wn = wid & 3;
  const int lr = lane & 15, lg = lane >> 4;

  // ---- 2D chunk XCD mapping: xcd owns CH_M x CH_N chunk, bn-fastest ----
  const int xcd = blockIdx.x & 7;
  const int idx = blockIdx.x >> 3;
  const int ncn = NBn / CH_N;
  const int cm = xcd / ncn, cn = xcd % ncn;
  const int bm = cm * CH_M + idx / CH_N;
  const int bn = cn * CH_N + idx % CH_N;

  const int NT = K >> 5;

  // ---- staging source addresses (pre-swizzled global, linear LDS dest) ----
  const int L = tid * 16;                            // byte within 8KB chunk
  const int rl = L >> 6;                             // row within chunk
  const int cbs = (L & 63) ^ (((rl >> 1) & 3) << 4); // logical col byte
  const bf16* sA0 = A + (size_t)(bm * 256 + rl) * K + (cbs >> 1);
  const bf16* sA1 = A + (size_t)(bm * 256 + 128 + rl) * K + (cbs >> 1);
  const bf16* sB0 = B + (size_t)(bn * BN_ + rl) * K + (cbs >> 1);
  const bf16* sB1 = B + (size_t)(bn * BN_ + (CHUNKS_B == 2 ? 128 : 0) + rl) * K + (cbs >> 1);

  char* ldsA = (char*)Alds;
  char* ldsB = (char*)Blds;
  const int wb = wid * 1024;  // wave-uniform dest offset

  // ---- ds_read bases (swizzled) ----
  const int cbr = (lg * 16) ^ (((lr >> 1) & 3) << 4);
  const char* ArdB = (const char*)Alds + (wm * 128 + lr) * 64 + cbr;
  const char* BrdB = (const char*)Blds + (wn * WN_TILE + lr) * 64 + cbr;

  f32x4 acc[8][NREP] = {};

  // ---- prologue: stage tiles 0,1,2 ----
#pragma unroll
  for (int t = 0; t < 3; ++t) {
    const size_t ko = (size_t)t << 5;
    gl_lds16(sA0 + ko, ldsA + t * 16384 + wb);
    gl_lds16(sA1 + ko, ldsA + t * 16384 + 8192 + wb);
    gl_lds16(sB0 + ko, ldsB + t * SLOTB + wb);
    if constexpr (CHUNKS_B == 2)
      gl_lds16(sB1 + ko, ldsB + t * SLOTB + 8192 + wb);
  }
  if constexpr (CHUNKS_B == 2) ASM_VMCNT(8); else ASM_VMCNT(6);
  __builtin_amdgcn_s_barrier();

  bf16x8 bfrag[NREP];
  for (int kt = 0; kt < NT; ++kt) {
    const int sA = (kt & 3) * 16384;
    const int sB = (kt & 3) * SLOTB;
    const bool st = (kt + 3) < NT;
    const int dsl = (kt + 3) & 3;
    const size_t ko = (size_t)(kt + 3) << 5;

    // ---- phase A: m-frags 0..3 ----
    bf16x8 af[4];
#pragma unroll
    for (int mf = 0; mf < 4; ++mf)
      af[mf] = *(const bf16x8*)(ArdB + sA + mf * 1024);
#pragma unroll
    for (int nf = 0; nf < NREP; ++nf)
      bfrag[nf] = *(const bf16x8*)(BrdB + sB + nf * 1024);
    if (st) {
      gl_lds16(sA0 + ko, ldsA + dsl * 16384 + wb);
      gl_lds16(sA1 + ko, ldsA + dsl * 16384 + 8192 + wb);
    }
    __builtin_amdgcn_s_barrier();
    asm volatile("s_waitcnt lgkmcnt(0)" ::: "memory");
    __builtin_amdgcn_sched_barrier(0);
    __builtin_amdgcn_s_setprio(1);
#pragma unroll
    for (int mf = 0; mf < 4; ++mf)
#pragma unroll
      for (int nf = 0; nf < NREP; ++nf)
        acc[mf][nf] = __builtin_amdgcn_mfma_f32_16x16x32_bf16(
            af[mf], bfrag[nf], acc[mf][nf], 0, 0, 0);
    __builtin_amdgcn_s_setprio(0);
    __builtin_amdgcn_s_barrier();

    // ---- phase B: m-frags 4..7 ----
#pragma unroll
    for (int mf = 0; mf < 4; ++mf)
      af[mf] = *(const bf16x8*)(ArdB + sA + (4 + mf) * 1024);
    if (st) {
      gl_lds16(sB0 + ko, ldsB + dsl * SLOTB + wb);
      if constexpr (CHUNKS_B == 2)
        gl_lds16(sB1 + ko, ldsB + dsl * SLOTB + 8192 + wb);
    }
    __builtin_amdgcn_s_barrier();
    asm volatile("s_waitcnt lgkmcnt(0)" ::: "memory");
    __builtin_amdgcn_sched_barrier(0);
    __builtin_amdgcn_s_setprio(1);
#pragma unroll
    for (int mf = 0; mf < 4; ++mf)
#pragma unroll
      for (int nf = 0; nf < NREP; ++nf)
        acc[4 + mf][nf] = __builtin_amdgcn_mfma_f32_16x16x32_bf16(
            af[mf], bfrag[nf], acc[4 + mf][nf], 0, 0, 0);
    __builtin_amdgcn_s_setprio(0);
    // tile-end counted wait: next tile resident; prefetched loads in flight
    if (st) {
      if constexpr (CHUNKS_B == 2) ASM_VMCNT(8); else ASM_VMCNT(6);
    } else if (kt + 2 < NT) {
      if constexpr (CHUNKS_B == 2) ASM_VMCNT(4); else ASM_VMCNT(3);
    } else if (kt + 1 < NT) {
      ASM_VMCNT(0);
    }
    __builtin_amdgcn_s_barrier();
  }

  // ---- epilogue ----
  const int colb = bn * BN_ + wn * WN_TILE;
  const int rowb = bm * 256 + wm * 128 + lg * 4;
#pragma unroll
  for (int mf = 0; mf < 8; ++mf) {
#pragma unroll
    for (int nf = 0; nf < NREP; ++nf) {
      const int col = colb + nf * 16 + lr;
      const float bv = bias[col];
#pragma unroll
      for (int r = 0; r < 4; ++r) {
        const int row = rowb + mf * 16 + r;
        const float v = acc[mf][nf][r] + bv;
        if (MODE == 0) {
          const float gl = 0.5f * v * (1.0f + erff(v * 0.7071067811865475f));
          Hout[(size_t)row * N + col] = (bf16)gl;
        } else {
          const float gv = gate[(size_t)row * 8 + gidx];
          const size_t oi = (size_t)row * N + col;
          if (MODE == 1)
            Fout[oi] += gv * v;
          else
            Fout[oi] = gv * v;
        }
      }
    }
  }
}

extern "C" void kernel_launch(void* const* d_in, const int* in_sizes, int n_in,
                              void* d_out, int out_size, void* d_ws,
                              size_t ws_size, hipStream_t stream) {
  const float* x = (const float*)d_in[0];
  const float* spec_w1 = (const float*)d_in[1];
  const float* spec_b1 = (const float*)d_in[2];
  const float* spec_w2 = (const float*)d_in[3];
  const float* spec_b2 = (const float*)d_in[4];
  const float* spec_rw = (const float*)d_in[5];
  const float* spec_rb = (const float*)d_in[6];
  const float* shr_w1 = (const float*)d_in[7];
  const float* shr_b1 = (const float*)d_in[8];
  const float* shr_w2 = (const float*)d_in[9];
  const float* shr_b2 = (const float*)d_in[10];
  const float* shr_rw = (const float*)d_in[11];
  const float* shr_rb = (const float*)d_in[12];
  float* out = (float*)d_out;

  char* ws = (char*)d_ws;
  const size_t SZ_X = (size_t)T_TOK * DDIM * 2;
  const size_t SZ_W = (size_t)6 * DDIM * HDIM * 2;
  bf16* xb = (bf16*)ws;
  bf16* w1t = (bf16*)(ws + SZ_X);
  bf16* w2t = (bf16*)(ws + SZ_X + SZ_W);
  bf16* hbuf = (bf16*)(ws + SZ_X + 2 * SZ_W);
  float* gate = (float*)(ws + SZ_X + 2 * SZ_W + (size_t)T_TOK * HDIM * 2);
  float* auxg = gate + (size_t)T_TOK * 8;

  init_aux<<<1, 64, 0, stream>>>(auxg);
  convert_x<<<(T_TOK * DDIM) / 2048, 256, 0, stream>>>(x, xb);
  transpose_convert<<<dim3(HDIM / 32, DDIM / 32, 4), 256, 0, stream>>>(
      spec_w1, w1t, DDIM, HDIM);
  transpose_convert<<<dim3(HDIM / 32, DDIM / 32, 2), 256, 0, stream>>>(
      shr_w1, w1t + (size_t)4 * DDIM * HDIM, DDIM, HDIM);
  transpose_convert<<<dim3(DDIM / 32, HDIM / 32, 4), 256, 0, stream>>>(
      spec_w2, w2t, HDIM, DDIM);
  transpose_convert<<<dim3(DDIM / 32, HDIM / 32, 2), 256, 0, stream>>>(
      shr_w2, w2t + (size_t)4 * DDIM * HDIM, HDIM, DDIM);
  router_kernel<<<T_TOK / 4, 256, 0, stream>>>(x, spec_rw, spec_rb, shr_rw,
                                               shr_rb, gate, auxg);

  for (int e = 0; e < 6; ++e) {
    const bf16* w1e = w1t + (size_t)e * DDIM * HDIM;
    const bf16* w2e = w2t + (size_t)e * DDIM * HDIM;
    const float* b1e =
        (e < 4) ? spec_b1 + (size_t)e * HDIM : shr_b1 + (size_t)(e - 4) * HDIM;
    const float* b2e =
        (e < 4) ? spec_b2 + (size_t)e * DDIM : shr_b2 + (size_t)(e - 4) * DDIM;

    // gemm1: [8192,1024] x [4096,1024]^T -> h, grid 32x16=512, chunk 8x8
    gemm8p<256, 0><<<512, 512, 0, stream>>>(xb, w1e, T_TOK, HDIM, DDIM, b1e,
                                            hbuf, nullptr, nullptr, 0,
                                            16, 8, 8);
    // gemm2: [8192,4096] x [1024,4096]^T -> out, grid 32x8=256, chunk 8x4
    if (e == 0)
      gemm8p<128, 2><<<256, 512, 0, stream>>>(hbuf, w2e, T_TOK, DDIM, HDIM,
                                              b2e, nullptr, out, gate, e,
                                              8, 8, 4);
    else
      gemm8p<128, 1><<<256, 512, 0, stream>>>(hbuf, w2e, T_TOK, DDIM, HDIM,
                                              b2e, nullptr, out, gate, e,
                                              8, 8, 4);
  }
  aux_finalize<<<1, 1, 0, stream>>>(auxg, out + (size_t)T_TOK * DDIM);
}

// Round 4
// 1232.334 us; speedup vs baseline: 1.2702x; 1.0721x over previous
//
#include <hip/hip_runtime.h>
#include <hip/hip_bf16.h>

#define T_TOK 8192
#define DDIM 1024
#define HDIM 4096

typedef __bf16 bf16;
typedef bf16 bf16x8 __attribute__((ext_vector_type(8)));
typedef float f32x4 __attribute__((ext_vector_type(4)));

#define ASM_VMCNT(n) asm volatile("s_waitcnt vmcnt(" #n ")" ::: "memory")

__device__ __forceinline__ void gl_lds16(const void* g, void* l) {
  __builtin_amdgcn_global_load_lds(
      (const __attribute__((address_space(1))) unsigned int*)g,
      (__attribute__((address_space(3))) unsigned int*)l, 16, 0, 0);
}

// ---------------- x fp32 -> bf16 ----------------
__global__ __launch_bounds__(256) void convert_x(const float* __restrict__ x,
                                                 bf16* __restrict__ xb) {
  const size_t i = ((size_t)blockIdx.x * 256 + threadIdx.x) * 8;
  const float4 v0 = *(const float4*)(x + i);
  const float4 v1 = *(const float4*)(x + i + 4);
  bf16x8 o;
  o[0] = (bf16)v0.x; o[1] = (bf16)v0.y; o[2] = (bf16)v0.z; o[3] = (bf16)v0.w;
  o[4] = (bf16)v1.x; o[5] = (bf16)v1.y; o[6] = (bf16)v1.z; o[7] = (bf16)v1.w;
  *(bf16x8*)(xb + i) = o;
}

// ---------------- weight transpose + convert: src [R,C] f32 -> dst [C,R] bf16
__global__ __launch_bounds__(256) void transpose_convert(
    const float* __restrict__ src, bf16* __restrict__ dst, int R, int C) {
  __shared__ float tile[32][33];
  const size_t mat = (size_t)blockIdx.z * R * C;
  const int c0 = blockIdx.x * 32, r0 = blockIdx.y * 32;
  const int tx = threadIdx.x & 31, ty = threadIdx.x >> 5;  // 32 x 8
#pragma unroll
  for (int i = 0; i < 4; ++i)
    tile[ty + 8 * i][tx] =
        src[mat + (size_t)(r0 + ty + 8 * i) * C + c0 + tx];
  __syncthreads();
#pragma unroll
  for (int i = 0; i < 4; ++i)
    dst[mat + (size_t)(c0 + ty + 8 * i) * R + r0 + tx] =
        (bf16)tile[tx][ty + 8 * i];
}

// ---------------- router: softmax/top2/gates + aux sums ----------------
__global__ __launch_bounds__(256) void router_kernel(
    const float* __restrict__ x, const float* __restrict__ srw,
    const float* __restrict__ srb, const float* __restrict__ hrw,
    const float* __restrict__ hrb, float* __restrict__ gate,
    float* __restrict__ auxg) {
  __shared__ float saux[8];
  if (threadIdx.x < 8) saux[threadIdx.x] = 0.0f;
  __syncthreads();

  const int lane = threadIdx.x & 63;
  const int w = threadIdx.x >> 6;
  const int t = blockIdx.x * 4 + w;

  const float* xr = x + (size_t)t * DDIM;
  float p0 = 0, p1 = 0, p2 = 0, p3 = 0, p4 = 0, p5 = 0;
#pragma unroll
  for (int c = 0; c < 4; ++c) {
    const int d = c * 256 + lane * 4;
    const float4 xv = *(const float4*)(xr + d);
    const float xa[4] = {xv.x, xv.y, xv.z, xv.w};
#pragma unroll
    for (int j = 0; j < 4; ++j) {
      const float xd = xa[j];
      const float4 r4 = *(const float4*)(srw + (size_t)(d + j) * 4);
      p0 += xd * r4.x; p1 += xd * r4.y; p2 += xd * r4.z; p3 += xd * r4.w;
      const float2 r2 = *(const float2*)(hrw + (size_t)(d + j) * 2);
      p4 += xd * r2.x; p5 += xd * r2.y;
    }
  }
#pragma unroll
  for (int off = 32; off >= 1; off >>= 1) {
    p0 += __shfl_xor(p0, off);
    p1 += __shfl_xor(p1, off);
    p2 += __shfl_xor(p2, off);
    p3 += __shfl_xor(p3, off);
    p4 += __shfl_xor(p4, off);
    p5 += __shfl_xor(p5, off);
  }
  if (lane == 0) {
    const float l0 = p0 + srb[0], l1 = p1 + srb[1];
    const float l2 = p2 + srb[2], l3 = p3 + srb[3];
    const float m = fmaxf(fmaxf(l0, l1), fmaxf(l2, l3));
    const float e0 = expf(l0 - m), e1 = expf(l1 - m);
    const float e2 = expf(l2 - m), e3 = expf(l3 - m);
    const float s = e0 + e1 + e2 + e3;
    float pr[4] = {e0 / s, e1 / s, e2 / s, e3 / s};
    int i1 = 0; float v1 = pr[0];
#pragma unroll
    for (int e = 1; e < 4; ++e) if (pr[e] > v1) { v1 = pr[e]; i1 = e; }
    int i2 = -1; float v2 = -1.0f;
#pragma unroll
    for (int e = 0; e < 4; ++e)
      if (e != i1 && pr[e] > v2) { v2 = pr[e]; i2 = e; }
    float g[4] = {0, 0, 0, 0};
    g[i1] = v1; g[i2] = v2;
    float* gr = gate + (size_t)t * 8;
    gr[0] = g[0]; gr[1] = g[1]; gr[2] = g[2]; gr[3] = g[3];
    const float h0 = p4 + hrb[0], h1 = p5 + hrb[1];
    const float mh = fmaxf(h0, h1);
    const float q0 = expf(h0 - mh), q1 = expf(h1 - mh);
    const float qs = q0 + q1;
    gr[4] = q0 / qs; gr[5] = q1 / qs; gr[6] = 0; gr[7] = 0;
    atomicAdd(&saux[i1], 1.0f);
    atomicAdd(&saux[i2], 1.0f);
    atomicAdd(&saux[4 + 0], pr[0]);
    atomicAdd(&saux[4 + 1], pr[1]);
    atomicAdd(&saux[4 + 2], pr[2]);
    atomicAdd(&saux[4 + 3], pr[3]);
  }
  __syncthreads();
  if (threadIdx.x < 8) atomicAdd(&auxg[threadIdx.x], saux[threadIdx.x]);
}

__global__ void init_aux(float* auxg) {
  if (threadIdx.x < 8) auxg[threadIdx.x] = 0.0f;
}

__global__ void aux_finalize(const float* __restrict__ auxg,
                             float* __restrict__ outp) {
  float a = 0.0f;
#pragma unroll
  for (int e = 0; e < 4; ++e)
    a += (auxg[e] / (float)(T_TOK * 2)) * (auxg[4 + e] / (float)T_TOK);
  outp[0] = 4.0f * a;
}

// ---------------- pipelined GEMM  C = A[M,K] * B[N,K]^T  (bf16 in, f32 acc)
// BM=256, BK=32, 8 waves (2M x 4N). 4-deep ring of DISTINCT __shared__ arrays
// (compile-time slot indices via manual unroll-4), ONE barrier per K-tile,
// 32 MFMA per barrier, counted vmcnt (never 0 mid-loop), compiler-scheduled
// ds_read->MFMA interleave (no sched_barrier, no mid-phase lgkm drain).
// Quarter-wave-balanced swizzle: byte ^= ((row>>1)&3)<<4 within 64B rows.
// MODE 0: Hout = gelu(C + bias); 1: Fout += gate*(C+bias); 2: Fout = gate*(C+bias)
template <int BN_, int MODE>
__global__ __launch_bounds__(512, 2) void gemmk(
    const bf16* __restrict__ A, const bf16* __restrict__ B, int M, int N,
    int K, const float* __restrict__ bias, bf16* __restrict__ Hout,
    float* __restrict__ Fout, const float* __restrict__ gate, int gidx,
    int NBn, int CH_M, int CH_N) {
  constexpr int WN_TILE = BN_ / 4;     // per-wave N extent
  constexpr int NREP = BN_ / 64;       // 4 (BN256) or 2 (BN128)
  constexpr int CHUNKS_B = BN_ / 128;  // 8KB staging chunks per B tile

  __shared__ bf16 As0[256 * 32], As1[256 * 32], As2[256 * 32], As3[256 * 32];
  __shared__ bf16 Bs0[BN_ * 32], Bs1[BN_ * 32], Bs2[BN_ * 32], Bs3[BN_ * 32];

  const int tid = threadIdx.x;
  const int lane = tid & 63, wid = tid >> 6;
  const int wm = wid >> 2, wn = wid & 3;
  const int lr = lane & 15, lg = lane >> 4;

  // ---- 2D chunk XCD mapping ----
  const int xcd = blockIdx.x & 7;
  const int idx = blockIdx.x >> 3;
  const int ncn = NBn / CH_N;
  const int cm = xcd / ncn, cn = xcd % ncn;
  const int bm = cm * CH_M + idx / CH_N;
  const int bn = cn * CH_N + idx % CH_N;

  const int NT = K >> 5;

  // ---- staging source (pre-swizzled global, linear LDS dest) ----
  const int L = tid * 16;
  const int rl = L >> 6;
  const int cbs = (L & 63) ^ (((rl >> 1) & 3) << 4);
  const bf16* sA0 = A + (size_t)(bm * 256 + rl) * K + (cbs >> 1);
  const bf16* sA1 = A + (size_t)(bm * 256 + 128 + rl) * K + (cbs >> 1);
  const bf16* sB0 = B + (size_t)(bn * BN_ + rl) * K + (cbs >> 1);
  const bf16* sB1 = B + (size_t)(bn * BN_ + (CHUNKS_B == 2 ? 128 : 0) + rl) * K + (cbs >> 1);

  const int wb = wid * 1024;  // wave-uniform dest offset

  // ---- ds_read bases per slot (swizzled) ----
  const int cbr = (lg * 16) ^ (((lr >> 1) & 3) << 4);
  const int aoff = (wm * 128 + lr) * 64 + cbr;
  const int boff = (wn * WN_TILE + lr) * 64 + cbr;
  const char* Ard[4] = {(const char*)As0 + aoff, (const char*)As1 + aoff,
                        (const char*)As2 + aoff, (const char*)As3 + aoff};
  const char* Brd[4] = {(const char*)Bs0 + boff, (const char*)Bs1 + boff,
                        (const char*)Bs2 + boff, (const char*)Bs3 + boff};
  char* const Asl[4] = {(char*)As0, (char*)As1, (char*)As2, (char*)As3};
  char* const Bsl[4] = {(char*)Bs0, (char*)Bs1, (char*)Bs2, (char*)Bs3};

  f32x4 acc[8][NREP] = {};

  // ---- prologue: stage tiles 0,1,2 into slots 0,1,2 ----
  gl_lds16(sA0, Asl[0] + wb);
  gl_lds16(sA1, Asl[0] + 8192 + wb);
  gl_lds16(sB0, Bsl[0] + wb);
  if constexpr (CHUNKS_B == 2) gl_lds16(sB1, Bsl[0] + 8192 + wb);
  gl_lds16(sA0 + 32, Asl[1] + wb);
  gl_lds16(sA1 + 32, Asl[1] + 8192 + wb);
  gl_lds16(sB0 + 32, Bsl[1] + wb);
  if constexpr (CHUNKS_B == 2) gl_lds16(sB1 + 32, Bsl[1] + 8192 + wb);
  gl_lds16(sA0 + 64, Asl[2] + wb);
  gl_lds16(sA1 + 64, Asl[2] + 8192 + wb);
  gl_lds16(sB0 + 64, Bsl[2] + wb);
  if constexpr (CHUNKS_B == 2) gl_lds16(sB1 + 64, Bsl[2] + 8192 + wb);
  if constexpr (CHUNKS_B == 2) ASM_VMCNT(8); else ASM_VMCNT(6);
  __builtin_amdgcn_s_barrier();

  for (int kt0 = 0; kt0 < NT; kt0 += 4) {
#pragma unroll
    for (int u = 0; u < 4; ++u) {   // compile-time slot indices
      const int kt = kt0 + u;
      const int dsl = (u + 3) & 3;  // staged slot != read slot (u) always
      const bool st = (kt + 3) < NT;
      const size_t ko = (size_t)(kt + 3) << 5;

      // issue-early staging for tile kt+3
      if (st) {
        gl_lds16(sA0 + ko, Asl[dsl] + wb);
        gl_lds16(sA1 + ko, Asl[dsl] + 8192 + wb);
        gl_lds16(sB0 + ko, Bsl[dsl] + wb);
        if constexpr (CHUNKS_B == 2) gl_lds16(sB1 + ko, Bsl[dsl] + 8192 + wb);
      }

      // fragments for this K-tile (compiler interleaves lgkm waits into MFMA)
      bf16x8 af[8], bfr[NREP];
#pragma unroll
      for (int mf = 0; mf < 8; ++mf)
        af[mf] = *(const bf16x8*)(Ard[u] + mf * 1024);
#pragma unroll
      for (int nf = 0; nf < NREP; ++nf)
        bfr[nf] = *(const bf16x8*)(Brd[u] + nf * 1024);

#pragma unroll
      for (int mf = 0; mf < 8; ++mf)
#pragma unroll
        for (int nf = 0; nf < NREP; ++nf)
          acc[mf][nf] = __builtin_amdgcn_mfma_f32_16x16x32_bf16(
              af[mf], bfr[nf], acc[mf][nf], 0, 0, 0);

      // counted tile-end wait: tile kt+1 resident, prefetches stay in flight
      if (st) {
        if constexpr (CHUNKS_B == 2) ASM_VMCNT(8); else ASM_VMCNT(6);
      } else if (kt + 2 < NT) {
        if constexpr (CHUNKS_B == 2) ASM_VMCNT(4); else ASM_VMCNT(3);
      } else if (kt + 1 < NT) {
        ASM_VMCNT(0);
      }
      // ring-reuse fence: own ds_reads done before slot handoff (cost ~0 here)
      asm volatile("s_waitcnt lgkmcnt(0)" ::: "memory");
      __builtin_amdgcn_s_barrier();
    }
  }

  // ---- epilogue ----
  const int colb = bn * BN_ + wn * WN_TILE;
  const int rowb = bm * 256 + wm * 128 + lg * 4;
  float bv[NREP];
#pragma unroll
  for (int nf = 0; nf < NREP; ++nf) bv[nf] = bias[colb + nf * 16 + lr];
#pragma unroll
  for (int mf = 0; mf < 8; ++mf) {
    if constexpr (MODE == 0) {
#pragma unroll
      for (int nf = 0; nf < NREP; ++nf) {
        const int col = colb + nf * 16 + lr;
#pragma unroll
        for (int r = 0; r < 4; ++r) {
          const int row = rowb + mf * 16 + r;
          const float v = acc[mf][nf][r] + bv[nf];
          const float gl = 0.5f * v * (1.0f + erff(v * 0.7071067811865475f));
          Hout[(size_t)row * N + col] = (bf16)gl;
        }
      }
    } else {
      float gv[4];
#pragma unroll
      for (int r = 0; r < 4; ++r)
        gv[r] = gate[(size_t)(rowb + mf * 16 + r) * 8 + gidx];
#pragma unroll
      for (int nf = 0; nf < NREP; ++nf) {
        const int col = colb + nf * 16 + lr;
#pragma unroll
        for (int r = 0; r < 4; ++r) {
          const int row = rowb + mf * 16 + r;
          const float v = acc[mf][nf][r] + bv[nf];
          const size_t oi = (size_t)row * N + col;
          if constexpr (MODE == 1)
            Fout[oi] += gv[r] * v;
          else
            Fout[oi] = gv[r] * v;
        }
      }
    }
  }
}

extern "C" void kernel_launch(void* const* d_in, const int* in_sizes, int n_in,
                              void* d_out, int out_size, void* d_ws,
                              size_t ws_size, hipStream_t stream) {
  const float* x = (const float*)d_in[0];
  const float* spec_w1 = (const float*)d_in[1];
  const float* spec_b1 = (const float*)d_in[2];
  const float* spec_w2 = (const float*)d_in[3];
  const float* spec_b2 = (const float*)d_in[4];
  const float* spec_rw = (const float*)d_in[5];
  const float* spec_rb = (const float*)d_in[6];
  const float* shr_w1 = (const float*)d_in[7];
  const float* shr_b1 = (const float*)d_in[8];
  const float* shr_w2 = (const float*)d_in[9];
  const float* shr_b2 = (const float*)d_in[10];
  const float* shr_rw = (const float*)d_in[11];
  const float* shr_rb = (const float*)d_in[12];
  float* out = (float*)d_out;

  char* ws = (char*)d_ws;
  const size_t SZ_X = (size_t)T_TOK * DDIM * 2;
  const size_t SZ_W = (size_t)6 * DDIM * HDIM * 2;
  bf16* xb = (bf16*)ws;
  bf16* w1t = (bf16*)(ws + SZ_X);
  bf16* w2t = (bf16*)(ws + SZ_X + SZ_W);
  bf16* hbuf = (bf16*)(ws + SZ_X + 2 * SZ_W);
  float* gate = (float*)(ws + SZ_X + 2 * SZ_W + (size_t)T_TOK * HDIM * 2);
  float* auxg = gate + (size_t)T_TOK * 8;

  init_aux<<<1, 64, 0, stream>>>(auxg);
  convert_x<<<(T_TOK * DDIM) / 2048, 256, 0, stream>>>(x, xb);
  transpose_convert<<<dim3(HDIM / 32, DDIM / 32, 4), 256, 0, stream>>>(
      spec_w1, w1t, DDIM, HDIM);
  transpose_convert<<<dim3(HDIM / 32, DDIM / 32, 2), 256, 0, stream>>>(
      shr_w1, w1t + (size_t)4 * DDIM * HDIM, DDIM, HDIM);
  transpose_convert<<<dim3(DDIM / 32, HDIM / 32, 4), 256, 0, stream>>>(
      spec_w2, w2t, HDIM, DDIM);
  transpose_convert<<<dim3(DDIM / 32, HDIM / 32, 2), 256, 0, stream>>>(
      shr_w2, w2t + (size_t)4 * DDIM * HDIM, HDIM, DDIM);
  router_kernel<<<T_TOK / 4, 256, 0, stream>>>(x, spec_rw, spec_rb, shr_rw,
                                               shr_rb, gate, auxg);

  for (int e = 0; e < 6; ++e) {
    const bf16* w1e = w1t + (size_t)e * DDIM * HDIM;
    const bf16* w2e = w2t + (size_t)e * DDIM * HDIM;
    const float* b1e =
        (e < 4) ? spec_b1 + (size_t)e * HDIM : shr_b1 + (size_t)(e - 4) * HDIM;
    const float* b2e =
        (e < 4) ? spec_b2 + (size_t)e * DDIM : shr_b2 + (size_t)(e - 4) * DDIM;

    // gemm1: [8192,1024] x [4096,1024]^T -> h, grid 32x16=512, chunk 8x8
    gemmk<256, 0><<<512, 512, 0, stream>>>(xb, w1e, T_TOK, HDIM, DDIM, b1e,
                                           hbuf, nullptr, nullptr, 0,
                                           16, 8, 8);
    // gemm2: [8192,4096] x [1024,4096]^T -> out, grid 32x8=256, chunk 8x4
    if (e == 0)
      gemmk<128, 2><<<256, 512, 0, stream>>>(hbuf, w2e, T_TOK, DDIM, HDIM,
                                             b2e, nullptr, out, gate, e,
                                             8, 8, 4);
    else
      gemmk<128, 1><<<256, 512, 0, stream>>>(hbuf, w2e, T_TOK, DDIM, HDIM,
                                             b2e, nullptr, out, gate, e,
                                             8, 8, 4);
  }
  aux_finalize<<<1, 1, 0, stream>>>(auxg, out + (size_t)T_TOK * DDIM);
}

// Round 5
// 1194.981 us; speedup vs baseline: 1.3099x; 1.0313x over previous
//
#include <hip/hip_runtime.h>
#include <hip/hip_bf16.h>

#define T_TOK 8192
#define DDIM 1024
#define HDIM 4096

typedef __bf16 bf16;
typedef bf16 bf16x8 __attribute__((ext_vector_type(8)));
typedef float f32x4 __attribute__((ext_vector_type(4)));

#define ASM_VMCNT(n) asm volatile("s_waitcnt vmcnt(" #n ")" ::: "memory")
#define MFMA16(a, b, c) __builtin_amdgcn_mfma_f32_16x16x32_bf16((a), (b), (c), 0, 0, 0)

__device__ __forceinline__ void gl_lds16(const void* g, void* l) {
  __builtin_amdgcn_global_load_lds(
      (const __attribute__((address_space(1))) unsigned int*)g,
      (__attribute__((address_space(3))) unsigned int*)l, 16, 0, 0);
}

// ---------------- x fp32 -> bf16 ----------------
__global__ __launch_bounds__(256) void convert_x(const float* __restrict__ x,
                                                 bf16* __restrict__ xb) {
  const size_t i = ((size_t)blockIdx.x * 256 + threadIdx.x) * 8;
  const float4 v0 = *(const float4*)(x + i);
  const float4 v1 = *(const float4*)(x + i + 4);
  bf16x8 o;
  o[0] = (bf16)v0.x; o[1] = (bf16)v0.y; o[2] = (bf16)v0.z; o[3] = (bf16)v0.w;
  o[4] = (bf16)v1.x; o[5] = (bf16)v1.y; o[6] = (bf16)v1.z; o[7] = (bf16)v1.w;
  *(bf16x8*)(xb + i) = o;
}

// ---------------- weight transpose + convert: src [R,C] f32 -> dst [C,R] bf16
__global__ __launch_bounds__(256) void transpose_convert(
    const float* __restrict__ src, bf16* __restrict__ dst, int R, int C) {
  __shared__ float tile[32][33];
  const size_t mat = (size_t)blockIdx.z * R * C;
  const int c0 = blockIdx.x * 32, r0 = blockIdx.y * 32;
  const int tx = threadIdx.x & 31, ty = threadIdx.x >> 5;  // 32 x 8
#pragma unroll
  for (int i = 0; i < 4; ++i)
    tile[ty + 8 * i][tx] =
        src[mat + (size_t)(r0 + ty + 8 * i) * C + c0 + tx];
  __syncthreads();
#pragma unroll
  for (int i = 0; i < 4; ++i)
    dst[mat + (size_t)(c0 + ty + 8 * i) * R + r0 + tx] =
        (bf16)tile[tx][ty + 8 * i];
}

// ---------------- router: softmax/top2/gates + aux sums ----------------
__global__ __launch_bounds__(256) void router_kernel(
    const float* __restrict__ x, const float* __restrict__ srw,
    const float* __restrict__ srb, const float* __restrict__ hrw,
    const float* __restrict__ hrb, float* __restrict__ gate,
    float* __restrict__ auxg) {
  __shared__ float saux[8];
  if (threadIdx.x < 8) saux[threadIdx.x] = 0.0f;
  __syncthreads();

  const int lane = threadIdx.x & 63;
  const int w = threadIdx.x >> 6;
  const int t = blockIdx.x * 4 + w;

  const float* xr = x + (size_t)t * DDIM;
  float p0 = 0, p1 = 0, p2 = 0, p3 = 0, p4 = 0, p5 = 0;
#pragma unroll
  for (int c = 0; c < 4; ++c) {
    const int d = c * 256 + lane * 4;
    const float4 xv = *(const float4*)(xr + d);
    const float xa[4] = {xv.x, xv.y, xv.z, xv.w};
#pragma unroll
    for (int j = 0; j < 4; ++j) {
      const float xd = xa[j];
      const float4 r4 = *(const float4*)(srw + (size_t)(d + j) * 4);
      p0 += xd * r4.x; p1 += xd * r4.y; p2 += xd * r4.z; p3 += xd * r4.w;
      const float2 r2 = *(const float2*)(hrw + (size_t)(d + j) * 2);
      p4 += xd * r2.x; p5 += xd * r2.y;
    }
  }
#pragma unroll
  for (int off = 32; off >= 1; off >>= 1) {
    p0 += __shfl_xor(p0, off);
    p1 += __shfl_xor(p1, off);
    p2 += __shfl_xor(p2, off);
    p3 += __shfl_xor(p3, off);
    p4 += __shfl_xor(p4, off);
    p5 += __shfl_xor(p5, off);
  }
  if (lane == 0) {
    const float l0 = p0 + srb[0], l1 = p1 + srb[1];
    const float l2 = p2 + srb[2], l3 = p3 + srb[3];
    const float m = fmaxf(fmaxf(l0, l1), fmaxf(l2, l3));
    const float e0 = expf(l0 - m), e1 = expf(l1 - m);
    const float e2 = expf(l2 - m), e3 = expf(l3 - m);
    const float s = e0 + e1 + e2 + e3;
    float pr[4] = {e0 / s, e1 / s, e2 / s, e3 / s};
    int i1 = 0; float v1 = pr[0];
#pragma unroll
    for (int e = 1; e < 4; ++e) if (pr[e] > v1) { v1 = pr[e]; i1 = e; }
    int i2 = -1; float v2 = -1.0f;
#pragma unroll
    for (int e = 0; e < 4; ++e)
      if (e != i1 && pr[e] > v2) { v2 = pr[e]; i2 = e; }
    float g[4] = {0, 0, 0, 0};
    g[i1] = v1; g[i2] = v2;
    float* gr = gate + (size_t)t * 8;
    gr[0] = g[0]; gr[1] = g[1]; gr[2] = g[2]; gr[3] = g[3];
    const float h0 = p4 + hrb[0], h1 = p5 + hrb[1];
    const float mh = fmaxf(h0, h1);
    const float q0 = expf(h0 - mh), q1 = expf(h1 - mh);
    const float qs = q0 + q1;
    gr[4] = q0 / qs; gr[5] = q1 / qs; gr[6] = 0; gr[7] = 0;
    atomicAdd(&saux[i1], 1.0f);
    atomicAdd(&saux[i2], 1.0f);
    atomicAdd(&saux[4 + 0], pr[0]);
    atomicAdd(&saux[4 + 1], pr[1]);
    atomicAdd(&saux[4 + 2], pr[2]);
    atomicAdd(&saux[4 + 3], pr[3]);
  }
  __syncthreads();
  if (threadIdx.x < 8) atomicAdd(&auxg[threadIdx.x], saux[threadIdx.x]);
}

__global__ void init_aux(float* auxg) {
  if (threadIdx.x < 8) auxg[threadIdx.x] = 0.0f;
}

__global__ void aux_finalize(const float* __restrict__ auxg,
                             float* __restrict__ outp) {
  float a = 0.0f;
#pragma unroll
  for (int e = 0; e < 4; ++e)
    a += (auxg[e] / (float)(T_TOK * 2)) * (auxg[4 + e] / (float)T_TOK);
  outp[0] = 4.0f * a;
}

// ---------------- m201-style 4-phase pipelined GEMM ----------------
// C = A[M,K] * B[N,K]^T, bf16 in, f32 acc. BM=256, BK=64, 8 waves (2Mx4N),
// 2-deep LDS dbuf, per-phase {ds-subtile | stage-half | barrier | lgkm0 |
// setprio MFMA x16 setprio | barrier}, steady-state vmcnt(6) (BN256)/4 (BN128).
// Swizzle: byte ^= ((row&7)<<4) within 128B rows, pre-applied on global src.
// MODE 0: Hout = gelu(C+bias); 1: Fout += gate*(C+bias); 2: Fout = gate*(C+bias)
template <int BN_, int MODE>
__global__ __launch_bounds__(512, 2) void gemm4p(
    const bf16* __restrict__ A, const bf16* __restrict__ B, int M, int N,
    int K, const float* __restrict__ bias, bf16* __restrict__ Hout,
    float* __restrict__ Fout, const float* __restrict__ gate, int gidx,
    int NBn, int CH_M, int CH_N) {
  constexpr int NREP = BN_ / 64;   // 4 (BN256) / 2 (BN128)
  constexpr int NHF = NREP / 2;    // frags per n-half
  constexpr int WNT = BN_ / 4;     // per-wave N extent
  constexpr int ABYTES = 256 * 64 * 2;  // 32 KB per dbuf slot
  constexpr int BBYTES = BN_ * 64 * 2;  // 32/16 KB

  __shared__ __align__(1024) bf16 Alds[2 * 256 * 64];
  __shared__ __align__(1024) bf16 Blds[2 * BN_ * 64];

  const int tid = threadIdx.x;
  const int lane = tid & 63, wid = tid >> 6;
  const int wm = wid >> 2, wn = wid & 3;
  const int lr = lane & 15, lg = lane >> 4;

  // ---- 2D chunk XCD mapping (verified R3) ----
  const int xcd = blockIdx.x & 7;
  const int idx = blockIdx.x >> 3;
  const int ncn = NBn / CH_N;
  const int cm = xcd / ncn, cn = xcd % ncn;
  const int bm = cm * CH_M + idx / CH_N;
  const int bn = cn * CH_N + idx % CH_N;

  const int NT = K >> 6;

  // ---- staging source (pre-swizzled global, linear LDS dest) ----
  const int L = tid * 16;                        // byte in 8KB chunk (64 rows x 128B)
  const int rl = L >> 7;                         // row 0..63 within chunk
  const int colb = (L & 127) ^ ((rl & 7) << 4);  // swizzled col byte
  const bf16* sA = A + (size_t)(bm * 256 + rl) * K + (colb >> 1);
  const bf16* sB = B + (size_t)(bn * BN_ + rl) * K + (colb >> 1);

  char* const ldsA = (char*)Alds;
  char* const ldsB = (char*)Blds;
  const int wb = wid * 1024;
  char* const stA[2] = {ldsA + wb, ldsA + ABYTES + wb};
  char* const stB[2] = {ldsB + wb, ldsB + BBYTES + wb};

  // ---- ds_read bases: ks0/ks1 per dbuf slot (swizzle key = (lr&7)<<4) ----
  const int ax0 = (lg * 16) ^ ((lr & 7) << 4);
  const int ax1 = ax0 ^ 64;
  const int aro = (wm * 128 + lr) * 128;
  const int bro = (wn * WNT + lr) * 128;
  const char* const Ak0[2] = {ldsA + aro + ax0, ldsA + ABYTES + aro + ax0};
  const char* const Ak1[2] = {ldsA + aro + ax1, ldsA + ABYTES + aro + ax1};
  const char* const Bk0[2] = {ldsB + bro + ax0, ldsB + BBYTES + bro + ax0};
  const char* const Bk1[2] = {ldsB + bro + ax1, ldsB + BBYTES + bro + ax1};

  f32x4 acc[8][NREP] = {};

  // ---- prologue: T0 {Ah0,Ah1,Bh0,Bh1}, then T1 {Bh0,Bh1,Ah0} ----
  gl_lds16(sA, stA[0]);
  gl_lds16(sA + (size_t)64 * K, stA[0] + 8192);
  gl_lds16(sA + (size_t)128 * K, stA[0] + 16384);
  gl_lds16(sA + (size_t)192 * K, stA[0] + 24576);
  if constexpr (BN_ == 256) {
    gl_lds16(sB, stB[0]);
    gl_lds16(sB + (size_t)64 * K, stB[0] + 8192);
    gl_lds16(sB + (size_t)128 * K, stB[0] + 16384);
    gl_lds16(sB + (size_t)192 * K, stB[0] + 24576);
    gl_lds16(sB + 64, stB[1]);
    gl_lds16(sB + (size_t)64 * K + 64, stB[1] + 8192);
    gl_lds16(sB + (size_t)128 * K + 64, stB[1] + 16384);
    gl_lds16(sB + (size_t)192 * K + 64, stB[1] + 24576);
  } else {
    gl_lds16(sB, stB[0]);
    gl_lds16(sB + (size_t)64 * K, stB[0] + 8192);
    gl_lds16(sB + 64, stB[1]);
    gl_lds16(sB + (size_t)64 * K + 64, stB[1] + 8192);
  }
  gl_lds16(sA + 64, stA[1]);
  gl_lds16(sA + (size_t)64 * K + 64, stA[1] + 8192);
  if constexpr (BN_ == 256) ASM_VMCNT(6); else ASM_VMCNT(4);
  __builtin_amdgcn_s_barrier();

  for (int kt0 = 0; kt0 < NT; kt0 += 2) {
#pragma unroll
    for (int par = 0; par < 2; ++par) {
      const int kt = kt0 + par;
      const int cur = par, oth = par ^ 1;
      const bool st1 = (kt + 1) < NT, st2 = (kt + 2) < NT;
      const size_t ko1 = (size_t)(kt + 1) << 6, ko2 = (size_t)(kt + 2) << 6;
      const char* Ac0 = Ak0[cur]; const char* Ac1 = Ak1[cur];
      const char* Bc0 = Bk0[cur]; const char* Bc1 = Bk1[cur];

      bf16x8 af[4][2], bfr[NREP][2];

      // ---- phase 1: ds A(mh0)+B(nh0); stage A(kt+1)h1 -> oth ----
#pragma unroll
      for (int mf = 0; mf < 4; ++mf) {
        af[mf][0] = *(const bf16x8*)(Ac0 + mf * 2048);
        af[mf][1] = *(const bf16x8*)(Ac1 + mf * 2048);
      }
#pragma unroll
      for (int nf = 0; nf < NHF; ++nf) {
        bfr[nf][0] = *(const bf16x8*)(Bc0 + nf * 2048);
        bfr[nf][1] = *(const bf16x8*)(Bc1 + nf * 2048);
      }
      if (st1) {
        gl_lds16(sA + (size_t)128 * K + ko1, stA[oth] + 16384);
        gl_lds16(sA + (size_t)192 * K + ko1, stA[oth] + 24576);
      }
      asm volatile("s_waitcnt lgkmcnt(8)" ::: "memory");
      __builtin_amdgcn_s_barrier();
      asm volatile("s_waitcnt lgkmcnt(0)" ::: "memory");
      __builtin_amdgcn_s_setprio(1);
#pragma unroll
      for (int mf = 0; mf < 4; ++mf)
#pragma unroll
        for (int nf = 0; nf < NHF; ++nf) {
          acc[mf][nf] = MFMA16(af[mf][0], bfr[nf][0], acc[mf][nf]);
          acc[mf][nf] = MFMA16(af[mf][1], bfr[nf][1], acc[mf][nf]);
        }
      __builtin_amdgcn_s_setprio(0);
      __builtin_amdgcn_s_barrier();

      // ---- phase 2: ds B(nh1); stage B(kt+2)h0 -> cur ----
#pragma unroll
      for (int nf = NHF; nf < NREP; ++nf) {
        bfr[nf][0] = *(const bf16x8*)(Bc0 + nf * 2048);
        bfr[nf][1] = *(const bf16x8*)(Bc1 + nf * 2048);
      }
      if (st2) {
        gl_lds16(sB + ko2, stB[cur]);
        if constexpr (BN_ == 256)
          gl_lds16(sB + (size_t)64 * K + ko2, stB[cur] + 8192);
      }
      __builtin_amdgcn_s_barrier();
      asm volatile("s_waitcnt lgkmcnt(0)" ::: "memory");
      __builtin_amdgcn_s_setprio(1);
#pragma unroll
      for (int mf = 0; mf < 4; ++mf)
#pragma unroll
        for (int nf = NHF; nf < NREP; ++nf) {
          acc[mf][nf] = MFMA16(af[mf][0], bfr[nf][0], acc[mf][nf]);
          acc[mf][nf] = MFMA16(af[mf][1], bfr[nf][1], acc[mf][nf]);
        }
      __builtin_amdgcn_s_setprio(0);
      __builtin_amdgcn_s_barrier();

      // ---- phase 3: ds A(mh1); stage B(kt+2)h1 -> cur ----
#pragma unroll
      for (int mf = 0; mf < 4; ++mf) {
        af[mf][0] = *(const bf16x8*)(Ac0 + 8192 + mf * 2048);
        af[mf][1] = *(const bf16x8*)(Ac1 + 8192 + mf * 2048);
      }
      if (st2) {
        if constexpr (BN_ == 256) {
          gl_lds16(sB + (size_t)128 * K + ko2, stB[cur] + 16384);
          gl_lds16(sB + (size_t)192 * K + ko2, stB[cur] + 24576);
        } else {
          gl_lds16(sB + (size_t)64 * K + ko2, stB[cur] + 8192);
        }
      }
      __builtin_amdgcn_s_barrier();
      asm volatile("s_waitcnt lgkmcnt(0)" ::: "memory");
      __builtin_amdgcn_s_setprio(1);
#pragma unroll
      for (int mf = 0; mf < 4; ++mf)
#pragma unroll
        for (int nf = 0; nf < NHF; ++nf) {
          acc[4 + mf][nf] = MFMA16(af[mf][0], bfr[nf][0], acc[4 + mf][nf]);
          acc[4 + mf][nf] = MFMA16(af[mf][1], bfr[nf][1], acc[4 + mf][nf]);
        }
      __builtin_amdgcn_s_setprio(0);
      __builtin_amdgcn_s_barrier();

      // ---- phase 4: stage A(kt+2)h0 -> cur; MFMA (mh1,nh1); counted wait ----
      if (st2) {
        gl_lds16(sA + ko2, stA[cur]);
        gl_lds16(sA + (size_t)64 * K + ko2, stA[cur] + 8192);
      }
      __builtin_amdgcn_s_setprio(1);
#pragma unroll
      for (int mf = 0; mf < 4; ++mf)
#pragma unroll
        for (int nf = NHF; nf < NREP; ++nf) {
          acc[4 + mf][nf] = MFMA16(af[mf][0], bfr[nf][0], acc[4 + mf][nf]);
          acc[4 + mf][nf] = MFMA16(af[mf][1], bfr[nf][1], acc[4 + mf][nf]);
        }
      __builtin_amdgcn_s_setprio(0);
      if (st2) {
        if constexpr (BN_ == 256) ASM_VMCNT(6); else ASM_VMCNT(4);
        __builtin_amdgcn_s_barrier();
      } else if (st1) {
        ASM_VMCNT(0);
        __builtin_amdgcn_s_barrier();
      }
    }
  }

  // ---- epilogue (verified R4) ----
  const int colb2 = bn * BN_ + wn * WNT;
  const int rowb = bm * 256 + wm * 128 + lg * 4;
  float bv[NREP];
#pragma unroll
  for (int nf = 0; nf < NREP; ++nf) bv[nf] = bias[colb2 + nf * 16 + lr];
#pragma unroll
  for (int mf = 0; mf < 8; ++mf) {
    if constexpr (MODE == 0) {
#pragma unroll
      for (int nf = 0; nf < NREP; ++nf) {
        const int col = colb2 + nf * 16 + lr;
#pragma unroll
        for (int r = 0; r < 4; ++r) {
          const int row = rowb + mf * 16 + r;
          const float v = acc[mf][nf][r] + bv[nf];
          const float gl = 0.5f * v * (1.0f + erff(v * 0.7071067811865475f));
          Hout[(size_t)row * N + col] = (bf16)gl;
        }
      }
    } else {
      float gv[4];
#pragma unroll
      for (int r = 0; r < 4; ++r)
        gv[r] = gate[(size_t)(rowb + mf * 16 + r) * 8 + gidx];
#pragma unroll
      for (int nf = 0; nf < NREP; ++nf) {
        const int col = colb2 + nf * 16 + lr;
#pragma unroll
        for (int r = 0; r < 4; ++r) {
          const int row = rowb + mf * 16 + r;
          const float v = acc[mf][nf][r] + bv[nf];
          const size_t oi = (size_t)row * N + col;
          if constexpr (MODE == 1)
            Fout[oi] += gv[r] * v;
          else
            Fout[oi] = gv[r] * v;
        }
      }
    }
  }
}

extern "C" void kernel_launch(void* const* d_in, const int* in_sizes, int n_in,
                              void* d_out, int out_size, void* d_ws,
                              size_t ws_size, hipStream_t stream) {
  const float* x = (const float*)d_in[0];
  const float* spec_w1 = (const float*)d_in[1];
  const float* spec_b1 = (const float*)d_in[2];
  const float* spec_w2 = (const float*)d_in[3];
  const float* spec_b2 = (const float*)d_in[4];
  const float* spec_rw = (const float*)d_in[5];
  const float* spec_rb = (const float*)d_in[6];
  const float* shr_w1 = (const float*)d_in[7];
  const float* shr_b1 = (const float*)d_in[8];
  const float* shr_w2 = (const float*)d_in[9];
  const float* shr_b2 = (const float*)d_in[10];
  const float* shr_rw = (const float*)d_in[11];
  const float* shr_rb = (const float*)d_in[12];
  float* out = (float*)d_out;

  char* ws = (char*)d_ws;
  const size_t SZ_X = (size_t)T_TOK * DDIM * 2;
  const size_t SZ_W = (size_t)6 * DDIM * HDIM * 2;
  bf16* xb = (bf16*)ws;
  bf16* w1t = (bf16*)(ws + SZ_X);
  bf16* w2t = (bf16*)(ws + SZ_X + SZ_W);
  bf16* hbuf = (bf16*)(ws + SZ_X + 2 * SZ_W);
  float* gate = (float*)(ws + SZ_X + 2 * SZ_W + (size_t)T_TOK * HDIM * 2);
  float* auxg = gate + (size_t)T_TOK * 8;

  init_aux<<<1, 64, 0, stream>>>(auxg);
  convert_x<<<(T_TOK * DDIM) / 2048, 256, 0, stream>>>(x, xb);
  transpose_convert<<<dim3(HDIM / 32, DDIM / 32, 4), 256, 0, stream>>>(
      spec_w1, w1t, DDIM, HDIM);
  transpose_convert<<<dim3(HDIM / 32, DDIM / 32, 2), 256, 0, stream>>>(
      shr_w1, w1t + (size_t)4 * DDIM * HDIM, DDIM, HDIM);
  transpose_convert<<<dim3(DDIM / 32, HDIM / 32, 4), 256, 0, stream>>>(
      spec_w2, w2t, HDIM, DDIM);
  transpose_convert<<<dim3(DDIM / 32, HDIM / 32, 2), 256, 0, stream>>>(
      shr_w2, w2t + (size_t)4 * DDIM * HDIM, HDIM, DDIM);
  router_kernel<<<T_TOK / 4, 256, 0, stream>>>(x, spec_rw, spec_rb, shr_rw,
                                               shr_rb, gate, auxg);

  for (int e = 0; e < 6; ++e) {
    const bf16* w1e = w1t + (size_t)e * DDIM * HDIM;
    const bf16* w2e = w2t + (size_t)e * DDIM * HDIM;
    const float* b1e =
        (e < 4) ? spec_b1 + (size_t)e * HDIM : shr_b1 + (size_t)(e - 4) * HDIM;
    const float* b2e =
        (e < 4) ? spec_b2 + (size_t)e * DDIM : shr_b2 + (size_t)(e - 4) * DDIM;

    // gemm1: [8192,1024] x [4096,1024]^T -> h, grid 32x16=512, chunk 8x8
    gemm4p<256, 0><<<512, 512, 0, stream>>>(xb, w1e, T_TOK, HDIM, DDIM, b1e,
                                            hbuf, nullptr, nullptr, 0,
                                            16, 8, 8);
    // gemm2: [8192,4096] x [1024,4096]^T -> out, grid 32x8=256, chunk 8x4
    if (e == 0)
      gemm4p<128, 2><<<256, 512, 0, stream>>>(hbuf, w2e, T_TOK, DDIM, HDIM,
                                              b2e, nullptr, out, gate, e,
                                              8, 8, 4);
    else
      gemm4p<128, 1><<<256, 512, 0, stream>>>(hbuf, w2e, T_TOK, DDIM, HDIM,
                                              b2e, nullptr, out, gate, e,
                                              8, 8, 4);
  }
  aux_finalize<<<1, 1, 0, stream>>>(auxg, out + (size_t)T_TOK * DDIM);
}